// Round 4
// baseline (1767.163 us; speedup 1.0000x reference)
//
#include <hip/hip_runtime.h>
#include <cstdint>
#include <cstddef>

#define GN   16384
#define GIN  128
#define GOUT 64
#define LOG2E 1.44269504088896340736f

typedef __attribute__((ext_vector_type(8))) short short8;
typedef __attribute__((ext_vector_type(4))) float f32x4;
typedef __attribute__((ext_vector_type(4))) int   int4v;

__device__ __forceinline__ unsigned short f2bf(float f) {
  unsigned u = __float_as_uint(f);
  return (unsigned short)((u + 0x8000u) >> 16);   // round-half-up (cheap)
}

__device__ __forceinline__ unsigned short f2bf_rne(float f) {
  unsigned u = __float_as_uint(f);
  u += 0x7FFFu + ((u >> 16) & 1u);
  return (unsigned short)(u >> 16);
}

// ---------------------------------------------------------------------------
// prep: Wh = x@W (fp32 in regs), f_src/f_dst (pre-scaled by log2e),
//       WhB^T bf16 [64][N] for MFMA B-operand contiguity.
// ---------------------------------------------------------------------------
__global__ __launch_bounds__(256) void prep_kernel(
    const float* __restrict__ x, const float* __restrict__ w,
    const float* __restrict__ aw, unsigned short* __restrict__ whbt,
    float* __restrict__ fs2, float* __restrict__ fd2)
{
  __shared__ float ws[GIN * GOUT];          // 32 KB
  __shared__ float red[2][64][4];

  const int t = threadIdx.x;
  const int rb = blockIdx.x * 64;

  for (int i = t; i < (GIN * GOUT) / 4; i += 256)
    ((float4*)ws)[i] = ((const float4*)w)[i];
  __syncthreads();

  const int r = t & 63, s = t >> 6;
  const int row = rb + r;
  const float* xr = x + (size_t)row * GIN;

  float acc[16];
#pragma unroll
  for (int d = 0; d < 16; ++d) acc[d] = 0.f;

  for (int kk = 0; kk < GIN; kk += 4) {
    float4 xv = *(const float4*)(xr + kk);
    float xa[4] = {xv.x, xv.y, xv.z, xv.w};
#pragma unroll
    for (int u = 0; u < 4; ++u) {
#pragma unroll
      for (int d = 0; d < 16; ++d)
        acc[d] += xa[u] * ws[(kk + u) * GOUT + s * 16 + d];
    }
  }

  float psrc = 0.f, pdst = 0.f;
#pragma unroll
  for (int d = 0; d < 16; ++d) {
    const int dg = s * 16 + d;
    psrc += acc[d] * aw[dg];
    pdst += acc[d] * aw[GOUT + dg];
    whbt[(size_t)dg * GN + row] = f2bf_rne(acc[d]);
  }
  red[0][r][s] = psrc;
  red[1][r][s] = pdst;
  __syncthreads();
  if (s == 0) {
    float a_ = red[0][r][0] + red[0][r][1] + red[0][r][2] + red[0][r][3];
    float b_ = red[1][r][0] + red[1][r][1] + red[1][r][2] + red[1][r][3];
    fs2[row] = a_ * LOG2E;
    fd2[row] = b_ * LOG2E;
  }
}

// ---------------------------------------------------------------------------
// adj_compress: pure streaming. 32 int32 -> 1 uint32 bitmask word.
// bm[row][c/32] bit (c&31) = (adj[row][c] != 0). Nothing else in the kernel
// so the HBM read stream issues back-to-back at full BW (fillBuffer pattern).
// ---------------------------------------------------------------------------
__global__ __launch_bounds__(256) void adj_compress(
    const int* __restrict__ adj, unsigned* __restrict__ bm)
{
  const size_t t = (size_t)blockIdx.x * 256 + threadIdx.x;
  const int4v* p = (const int4v*)adj + t * 8;
  unsigned b = 0;
#pragma unroll
  for (int k = 0; k < 8; ++k) {
    int4v a = __builtin_nontemporal_load(p + k);
    b |= (a.x != 0) ? (1u << (4 * k + 0)) : 0u;
    b |= (a.y != 0) ? (1u << (4 * k + 1)) : 0u;
    b |= (a.z != 0) ? (1u << (4 * k + 2)) : 0u;
    b |= (a.w != 0) ? (1u << (4 * k + 3)) : 0u;
  }
  bm[t] = b;
}

// ---------------------------------------------------------------------------
// main v4: identical math to v3 but reads the 33.5 MB bitmask instead of the
// 1.07 GB adj -> kernel becomes VALU/MFMA-bound, tiny memory footprint.
// One wave per (32 rows, 1/8 column chunk). den via ones-MFMA. No LDS.
// ---------------------------------------------------------------------------
__global__ __launch_bounds__(256) void gat_main(
    const unsigned* __restrict__ bm, const unsigned short* __restrict__ whbt,
    const float* __restrict__ fs2, const float* __restrict__ fd2,
    float* __restrict__ num, float* __restrict__ den)
{
  const int wave  = blockIdx.x * 4 + (threadIdx.x >> 6);
  const int lane  = threadIdx.x & 63;
  const int strip = wave & 511;             // 512 strips of 32 rows
  const int chunk = wave >> 9;              // 8 column chunks
  const int m = lane & 15;
  const int q = lane >> 4;
  const int row0 = strip * 32 + m;
  const int row1 = row0 + 16;

  const float fs0 = fs2[row0];
  const float fs1 = fs2[row1];
  const int CW = GN / 8;                    // 2048 columns per chunk
  const int j0 = chunk * CW;

  const unsigned* __restrict__ bmr0 = bm + (size_t)row0 * (GN / 32);
  const unsigned* __restrict__ bmr1 = bm + (size_t)row1 * (GN / 32);
  const float4*   __restrict__ fdv  = (const float4*)fd2;
  const unsigned bsh = q * 8;

  f32x4 acc0a = {0,0,0,0}, acc1a = {0,0,0,0}, acc2a = {0,0,0,0}, acc3a = {0,0,0,0};
  f32x4 acc0b = {0,0,0,0}, acc1b = {0,0,0,0}, acc2b = {0,0,0,0}, acc3b = {0,0,0,0};
  f32x4 accda = {0,0,0,0}, accdb = {0,0,0,0};   // den accumulators

  short8 b_ones;
#pragma unroll
  for (int i = 0; i < 8; ++i) b_ones[i] = (short)0x3F80;  // bf16 1.0

  auto pcalc = [&](unsigned bit, float fd, float fs) -> unsigned short {
    float sv = fs + fd;
    float lv = fmaxf(sv, 0.02f * sv);       // lrelu (commutes with *log2e)
    float pe = __builtin_amdgcn_exp2f(lv);
    pe = bit ? pe : 0.f;
    return f2bf(pe);
  };

  auto mk_af = [&](unsigned mk, float4 fA, float4 fB, float fs) -> short8 {
    short8 af;
    af[0] = (short)pcalc(mk & 1u,   fA.x, fs);
    af[1] = (short)pcalc(mk & 2u,   fA.y, fs);
    af[2] = (short)pcalc(mk & 4u,   fA.z, fs);
    af[3] = (short)pcalc(mk & 8u,   fA.w, fs);
    af[4] = (short)pcalc(mk & 16u,  fB.x, fs);
    af[5] = (short)pcalc(mk & 32u,  fB.y, fs);
    af[6] = (short)pcalc(mk & 64u,  fB.z, fs);
    af[7] = (short)pcalc(mk & 128u, fB.w, fs);
    return af;
  };

#pragma unroll 2
  for (int j = j0; j < j0 + CW; j += 32) {
    const unsigned u0 = bmr0[j >> 5] >> bsh;   // 8 bits for this lane's cols
    const unsigned u1 = bmr1[j >> 5] >> bsh;
    const int i4 = (j >> 2) + (q << 1);
    float4 f0 = fdv[i4];
    float4 f1 = fdv[i4 + 1];

    const unsigned short* wb = whbt + j + q * 8;
    short8 b0 = *(const short8*)(wb + (size_t)(0  + m) * GN);
    short8 b1 = *(const short8*)(wb + (size_t)(16 + m) * GN);
    short8 b2 = *(const short8*)(wb + (size_t)(32 + m) * GN);
    short8 b3 = *(const short8*)(wb + (size_t)(48 + m) * GN);

    short8 af0 = mk_af(u0, f0, f1, fs0);
    short8 af1 = mk_af(u1, f0, f1, fs1);

    acc0a = __builtin_amdgcn_mfma_f32_16x16x32_bf16(af0, b0, acc0a, 0, 0, 0);
    acc1a = __builtin_amdgcn_mfma_f32_16x16x32_bf16(af0, b1, acc1a, 0, 0, 0);
    acc2a = __builtin_amdgcn_mfma_f32_16x16x32_bf16(af0, b2, acc2a, 0, 0, 0);
    acc3a = __builtin_amdgcn_mfma_f32_16x16x32_bf16(af0, b3, acc3a, 0, 0, 0);
    accda = __builtin_amdgcn_mfma_f32_16x16x32_bf16(af0, b_ones, accda, 0, 0, 0);
    acc0b = __builtin_amdgcn_mfma_f32_16x16x32_bf16(af1, b0, acc0b, 0, 0, 0);
    acc1b = __builtin_amdgcn_mfma_f32_16x16x32_bf16(af1, b1, acc1b, 0, 0, 0);
    acc2b = __builtin_amdgcn_mfma_f32_16x16x32_bf16(af1, b2, acc2b, 0, 0, 0);
    acc3b = __builtin_amdgcn_mfma_f32_16x16x32_bf16(af1, b3, acc3b, 0, 0, 0);
    accdb = __builtin_amdgcn_mfma_f32_16x16x32_bf16(af1, b_ones, accdb, 0, 0, 0);
  }

  // den: D[row=q*4+r][col=m] is col-independent for B=ones; lane m==0 writes.
  if (m == 0) {
#pragma unroll
    for (int r = 0; r < 4; ++r) {
      unsafeAtomicAdd(&den[strip * 32 + q * 4 + r],      accda[r]);
      unsafeAtomicAdd(&den[strip * 32 + 16 + q * 4 + r], accdb[r]);
    }
  }

  // num: C/D layout D[row = q*4 + r][col = lane&15]
  const int orow0 = strip * 32 + q * 4;
#pragma unroll
  for (int r = 0; r < 4; ++r) {
    float* nra = num + (size_t)(orow0 + r) * GOUT + m;
    unsafeAtomicAdd(nra + 0,  acc0a[r]);
    unsafeAtomicAdd(nra + 16, acc1a[r]);
    unsafeAtomicAdd(nra + 32, acc2a[r]);
    unsafeAtomicAdd(nra + 48, acc3a[r]);
    float* nrb = num + (size_t)(orow0 + 16 + r) * GOUT + m;
    unsafeAtomicAdd(nrb + 0,  acc0b[r]);
    unsafeAtomicAdd(nrb + 16, acc1b[r]);
    unsafeAtomicAdd(nrb + 32, acc2b[r]);
    unsafeAtomicAdd(nrb + 48, acc3b[r]);
  }
}

// ---------------------------------------------------------------------------
// finalize: out = elu(num / den)
// ---------------------------------------------------------------------------
__global__ __launch_bounds__(256) void fin_kernel(
    const float* __restrict__ num, const float* __restrict__ den,
    float* __restrict__ out)
{
  const int g = blockIdx.x * 256 + threadIdx.x;
  if (g < GN * GOUT) {
    float v = num[g] / den[g >> 6];
    out[g] = (v > 0.f) ? v : expm1f(v);
  }
}

extern "C" void kernel_launch(void* const* d_in, const int* in_sizes, int n_in,
                              void* d_out, int out_size, void* d_ws, size_t ws_size,
                              hipStream_t stream) {
  const float* x   = (const float*)d_in[0];
  const int*   adj = (const int*)d_in[1];
  const float* w   = (const float*)d_in[2];
  const float* aw  = (const float*)d_in[3];
  float* out = (float*)d_out;

  // ws layout (floats): num[N*64] | den[N] | fs2[N] | fd2[N] | whbt(bf16 64*N) | bm(u32 N*N/32)
  float* num = (float*)d_ws;
  float* den = num + (size_t)GN * GOUT;
  float* fs2 = den + GN;
  float* fd2 = fs2 + GN;
  unsigned short* whbt = (unsigned short*)(fd2 + GN);
  unsigned* bm = (unsigned*)(whbt + (size_t)GOUT * GN);
  // total ~40 MB of the 4 GiB ws

  hipMemsetAsync(num, 0, ((size_t)GN * GOUT + GN) * sizeof(float), stream);
  prep_kernel<<<GN / 64, 256, 0, stream>>>(x, w, aw, whbt, fs2, fd2);
  adj_compress<<<(GN / 32) * (GN / 256), 256, 0, stream>>>(adj, bm);
  gat_main<<<(GN / 32) * 8 / 4, 256, 0, stream>>>(bm, whbt, fs2, fd2, num, den);
  fin_kernel<<<(GN * GOUT) / 256, 256, 0, stream>>>(num, den, out);
}

// Round 5
// 1452.427 us; speedup vs baseline: 1.2167x; 1.2167x over previous
//
#include <hip/hip_runtime.h>
#include <cstdint>
#include <cstddef>

#define GN   16384
#define GIN  128
#define GOUT 64
#define LOG2E 1.44269504088896340736f

typedef __attribute__((ext_vector_type(8))) short short8;
typedef __attribute__((ext_vector_type(4))) float f32x4;
typedef __attribute__((ext_vector_type(4))) int   int4v;

__device__ __forceinline__ unsigned short f2bf(float f) {
  unsigned u = __float_as_uint(f);
  return (unsigned short)((u + 0x8000u) >> 16);   // round-half-up (cheap)
}

__device__ __forceinline__ unsigned short f2bf_rne(float f) {
  unsigned u = __float_as_uint(f);
  u += 0x7FFFu + ((u >> 16) & 1u);
  return (unsigned short)(u >> 16);
}

// ---------------------------------------------------------------------------
// prep: Wh = x@W (fp32 in regs), f_src/f_dst (pre-scaled by log2e), and
// Wh packed DIRECTLY into MFMA B-fragment order:
//   wpk[col_tile(512)][frag(4)][lane(64)][t(8)]  (bf16)
// where col = col_tile*32 + (lane>>4)*8 + t, out-dim d = frag*16 + (lane&15).
// A wave's B-operand load is then ONE contiguous 1 KB coalesced read.
// ---------------------------------------------------------------------------
__global__ __launch_bounds__(256) void prep_kernel(
    const float* __restrict__ x, const float* __restrict__ w,
    const float* __restrict__ aw, unsigned short* __restrict__ wpk,
    float* __restrict__ fs2, float* __restrict__ fd2)
{
  __shared__ float ws[GIN * GOUT];          // 32 KB
  __shared__ float red[2][64][4];

  const int t = threadIdx.x;
  const int rb = blockIdx.x * 64;

  for (int i = t; i < (GIN * GOUT) / 4; i += 256)
    ((float4*)ws)[i] = ((const float4*)w)[i];
  __syncthreads();

  const int r = t & 63, s = t >> 6;
  const int row = rb + r;
  const float* xr = x + (size_t)row * GIN;

  float acc[16];
#pragma unroll
  for (int d = 0; d < 16; ++d) acc[d] = 0.f;

  for (int kk = 0; kk < GIN; kk += 4) {
    float4 xv = *(const float4*)(xr + kk);
    float xa[4] = {xv.x, xv.y, xv.z, xv.w};
#pragma unroll
    for (int u = 0; u < 4; ++u) {
#pragma unroll
      for (int d = 0; d < 16; ++d)
        acc[d] += xa[u] * ws[(kk + u) * GOUT + s * 16 + d];
    }
  }

  // packed-fragment write: col = row, so
  // jc = row>>5, qq = (row&31)>>3, tt = row&7; d = s*16+dd -> frag f = d>>4,
  // n = d&15; element index = jc*4096 + f*1024 + (qq*16+n)*8 + tt.
  const int jc = row >> 5;
  const int qq = (row & 31) >> 3;
  const int tt = row & 7;
  float psrc = 0.f, pdst = 0.f;
#pragma unroll
  for (int d = 0; d < 16; ++d) {
    const int dg = s * 16 + d;
    psrc += acc[d] * aw[dg];
    pdst += acc[d] * aw[GOUT + dg];
    const int f = dg >> 4, n = dg & 15;
    wpk[(size_t)jc * 4096 + f * 1024 + (qq * 16 + n) * 8 + tt] = f2bf_rne(acc[d]);
  }
  red[0][r][s] = psrc;
  red[1][r][s] = pdst;
  __syncthreads();
  if (s == 0) {
    float a_ = red[0][r][0] + red[0][r][1] + red[0][r][2] + red[0][r][3];
    float b_ = red[1][r][0] + red[1][r][1] + red[1][r][2] + red[1][r][3];
    fs2[row] = a_ * LOG2E;
    fd2[row] = b_ * LOG2E;
  }
}

// ---------------------------------------------------------------------------
// main v5: fused again (direct nontemporal adj reads — R4 proved the adj
// stream is not the bottleneck). B-operands now come from the packed wpk:
// each of the 4 fragment loads is a single contiguous 1 KB wave-load
// (16 cache lines, 100% utilization) instead of 64 scattered lines.
// One wave per (32 rows, 1/8 column chunk); den via ones-MFMA; no LDS.
// ---------------------------------------------------------------------------
__global__ __launch_bounds__(256) void gat_main(
    const int* __restrict__ adj, const unsigned short* __restrict__ wpk,
    const float* __restrict__ fs2, const float* __restrict__ fd2,
    float* __restrict__ num, float* __restrict__ den)
{
  const int wave  = blockIdx.x * 4 + (threadIdx.x >> 6);
  const int lane  = threadIdx.x & 63;
  const int strip = wave & 511;             // 512 strips of 32 rows
  const int chunk = wave >> 9;              // 8 column chunks
  const int m = lane & 15;
  const int q = lane >> 4;
  const int row0 = strip * 32 + m;
  const int row1 = row0 + 16;

  const float fs0 = fs2[row0];
  const float fs1 = fs2[row1];
  const int CW = GN / 8;                    // 2048 columns per chunk
  const int j0 = chunk * CW;

  const int4v*  __restrict__ arow0 = (const int4v*)(adj + (size_t)row0 * GN);
  const int4v*  __restrict__ arow1 = (const int4v*)(adj + (size_t)row1 * GN);
  const float4* __restrict__ fdv   = (const float4*)fd2;
  const short8* __restrict__ wpk8  = (const short8*)wpk;

  f32x4 acc0a = {0,0,0,0}, acc1a = {0,0,0,0}, acc2a = {0,0,0,0}, acc3a = {0,0,0,0};
  f32x4 acc0b = {0,0,0,0}, acc1b = {0,0,0,0}, acc2b = {0,0,0,0}, acc3b = {0,0,0,0};
  f32x4 accda = {0,0,0,0}, accdb = {0,0,0,0};   // den accumulators

  short8 b_ones;
#pragma unroll
  for (int i = 0; i < 8; ++i) b_ones[i] = (short)0x3F80;  // bf16 1.0

  auto pcalc = [&](int a, float fd, float fs) -> unsigned short {
    float sv = fs + fd;
    float lv = fmaxf(sv, 0.02f * sv);       // lrelu (commutes with *log2e)
    float pe = __builtin_amdgcn_exp2f(lv);
    pe = (a != 0) ? pe : 0.f;
    return f2bf(pe);
  };

  auto mk_af = [&](int4v aA, int4v aB, float4 fA, float4 fB, float fs) -> short8 {
    short8 af;
    af[0] = (short)pcalc(aA.x, fA.x, fs);
    af[1] = (short)pcalc(aA.y, fA.y, fs);
    af[2] = (short)pcalc(aA.z, fA.z, fs);
    af[3] = (short)pcalc(aA.w, fA.w, fs);
    af[4] = (short)pcalc(aB.x, fB.x, fs);
    af[5] = (short)pcalc(aB.y, fB.y, fs);
    af[6] = (short)pcalc(aB.z, fB.z, fs);
    af[7] = (short)pcalc(aB.w, fB.w, fs);
    return af;
  };

#pragma unroll 2
  for (int j = j0; j < j0 + CW; j += 32) {
    const int i4 = (j >> 2) + (q << 1);
    int4v a00 = __builtin_nontemporal_load(arow0 + i4);
    int4v a01 = __builtin_nontemporal_load(arow0 + i4 + 1);
    int4v a10 = __builtin_nontemporal_load(arow1 + i4);
    int4v a11 = __builtin_nontemporal_load(arow1 + i4 + 1);
    float4 f0 = fdv[i4];
    float4 f1 = fdv[i4 + 1];

    // packed B fragments: 4 contiguous 1 KB wave-loads
    const short8* wb = wpk8 + (size_t)(j >> 5) * 512 + lane;
    short8 b0 = wb[0];
    short8 b1 = wb[128];
    short8 b2 = wb[256];
    short8 b3 = wb[384];

    short8 af0 = mk_af(a00, a01, f0, f1, fs0);
    short8 af1 = mk_af(a10, a11, f0, f1, fs1);

    acc0a = __builtin_amdgcn_mfma_f32_16x16x32_bf16(af0, b0, acc0a, 0, 0, 0);
    acc1a = __builtin_amdgcn_mfma_f32_16x16x32_bf16(af0, b1, acc1a, 0, 0, 0);
    acc2a = __builtin_amdgcn_mfma_f32_16x16x32_bf16(af0, b2, acc2a, 0, 0, 0);
    acc3a = __builtin_amdgcn_mfma_f32_16x16x32_bf16(af0, b3, acc3a, 0, 0, 0);
    accda = __builtin_amdgcn_mfma_f32_16x16x32_bf16(af0, b_ones, accda, 0, 0, 0);
    acc0b = __builtin_amdgcn_mfma_f32_16x16x32_bf16(af1, b0, acc0b, 0, 0, 0);
    acc1b = __builtin_amdgcn_mfma_f32_16x16x32_bf16(af1, b1, acc1b, 0, 0, 0);
    acc2b = __builtin_amdgcn_mfma_f32_16x16x32_bf16(af1, b2, acc2b, 0, 0, 0);
    acc3b = __builtin_amdgcn_mfma_f32_16x16x32_bf16(af1, b3, acc3b, 0, 0, 0);
    accdb = __builtin_amdgcn_mfma_f32_16x16x32_bf16(af1, b_ones, accdb, 0, 0, 0);
  }

  // den: D[row=q*4+r][col=m] is col-independent for B=ones; lane m==0 writes.
  if (m == 0) {
#pragma unroll
    for (int r = 0; r < 4; ++r) {
      unsafeAtomicAdd(&den[strip * 32 + q * 4 + r],      accda[r]);
      unsafeAtomicAdd(&den[strip * 32 + 16 + q * 4 + r], accdb[r]);
    }
  }

  // num: C/D layout D[row = q*4 + r][col = lane&15]
  const int orow0 = strip * 32 + q * 4;
#pragma unroll
  for (int r = 0; r < 4; ++r) {
    float* nra = num + (size_t)(orow0 + r) * GOUT + m;
    unsafeAtomicAdd(nra + 0,  acc0a[r]);
    unsafeAtomicAdd(nra + 16, acc1a[r]);
    unsafeAtomicAdd(nra + 32, acc2a[r]);
    unsafeAtomicAdd(nra + 48, acc3a[r]);
    float* nrb = num + (size_t)(orow0 + 16 + r) * GOUT + m;
    unsafeAtomicAdd(nrb + 0,  acc0b[r]);
    unsafeAtomicAdd(nrb + 16, acc1b[r]);
    unsafeAtomicAdd(nrb + 32, acc2b[r]);
    unsafeAtomicAdd(nrb + 48, acc3b[r]);
  }
}

// ---------------------------------------------------------------------------
// finalize: out = elu(num / den)
// ---------------------------------------------------------------------------
__global__ __launch_bounds__(256) void fin_kernel(
    const float* __restrict__ num, const float* __restrict__ den,
    float* __restrict__ out)
{
  const int g = blockIdx.x * 256 + threadIdx.x;
  if (g < GN * GOUT) {
    float v = num[g] / den[g >> 6];
    out[g] = (v > 0.f) ? v : expm1f(v);
  }
}

extern "C" void kernel_launch(void* const* d_in, const int* in_sizes, int n_in,
                              void* d_out, int out_size, void* d_ws, size_t ws_size,
                              hipStream_t stream) {
  const float* x   = (const float*)d_in[0];
  const int*   adj = (const int*)d_in[1];
  const float* w   = (const float*)d_in[2];
  const float* aw  = (const float*)d_in[3];
  float* out = (float*)d_out;

  // ws layout (floats): num[N*64] | den[N] | fs2[N] | fd2[N] | wpk(bf16 64*N)
  float* num = (float*)d_ws;
  float* den = num + (size_t)GN * GOUT;
  float* fs2 = den + GN;
  float* fd2 = fs2 + GN;
  unsigned short* wpk = (unsigned short*)(fd2 + GN);

  hipMemsetAsync(num, 0, ((size_t)GN * GOUT + GN) * sizeof(float), stream);
  prep_kernel<<<GN / 64, 256, 0, stream>>>(x, w, aw, wpk, fs2, fd2);
  gat_main<<<(GN / 32) * 8 / 4, 256, 0, stream>>>(adj, wpk, fs2, fd2, num, den);
  fin_kernel<<<(GN * GOUT) / 256, 256, 0, stream>>>(num, den, out);
}

// Round 7
// 1384.946 us; speedup vs baseline: 1.2760x; 1.0487x over previous
//
#include <hip/hip_runtime.h>
#include <cstdint>
#include <cstddef>

#define GN   16384
#define GIN  128
#define GOUT 64
#define NCH  8          // column chunks
#define LOG2E 1.44269504088896340736f

typedef __attribute__((ext_vector_type(8))) short short8;
typedef __attribute__((ext_vector_type(4))) float f32x4;
typedef __attribute__((ext_vector_type(4))) int   int4v;

__device__ __forceinline__ unsigned short f2bf(float f) {
  unsigned u = __float_as_uint(f);
  return (unsigned short)((u + 0x8000u) >> 16);   // round-half-up (cheap)
}

__device__ __forceinline__ unsigned short f2bf_rne(float f) {
  unsigned u = __float_as_uint(f);
  u += 0x7FFFu + ((u >> 16) & 1u);
  return (unsigned short)(u >> 16);
}

// ---------------------------------------------------------------------------
// prep (verified R5 version): Wh = x@W, f_src/f_dst (x log2e), Wh packed in
// MFMA B-fragment order: wpk[col_tile(512)][frag(4)][lane(64)][t(8)] bf16,
// col = col_tile*32 + (lane>>4)*8 + t, out-dim d = frag*16 + (lane&15).
// ---------------------------------------------------------------------------
__global__ __launch_bounds__(256) void prep_kernel(
    const float* __restrict__ x, const float* __restrict__ w,
    const float* __restrict__ aw, unsigned short* __restrict__ wpk,
    float* __restrict__ fs2, float* __restrict__ fd2)
{
  __shared__ float ws[GIN * GOUT];          // 32 KB
  __shared__ float red[2][64][4];

  const int t = threadIdx.x;
  const int rb = blockIdx.x * 64;

  for (int i = t; i < (GIN * GOUT) / 4; i += 256)
    ((float4*)ws)[i] = ((const float4*)w)[i];
  __syncthreads();

  const int r = t & 63, s = t >> 6;
  const int row = rb + r;
  const float* xr = x + (size_t)row * GIN;

  float acc[16];
#pragma unroll
  for (int d = 0; d < 16; ++d) acc[d] = 0.f;

  for (int kk = 0; kk < GIN; kk += 4) {
    float4 xv = *(const float4*)(xr + kk);
    float xa[4] = {xv.x, xv.y, xv.z, xv.w};
#pragma unroll
    for (int u = 0; u < 4; ++u) {
#pragma unroll
      for (int d = 0; d < 16; ++d)
        acc[d] += xa[u] * ws[(kk + u) * GOUT + s * 16 + d];
    }
  }

  const int jc = row >> 5;
  const int qq = (row & 31) >> 3;
  const int tt = row & 7;
  float psrc = 0.f, pdst = 0.f;
#pragma unroll
  for (int d = 0; d < 16; ++d) {
    const int dg = s * 16 + d;
    psrc += acc[d] * aw[dg];
    pdst += acc[d] * aw[GOUT + dg];
    const int f = dg >> 4, n = dg & 15;
    wpk[(size_t)jc * 4096 + f * 1024 + (qq * 16 + n) * 8 + tt] = f2bf_rne(acc[d]);
  }
  red[0][r][s] = psrc;
  red[1][r][s] = pdst;
  __syncthreads();
  if (s == 0) {
    float a_ = red[0][r][0] + red[0][r][1] + red[0][r][2] + red[0][r][3];
    float b_ = red[1][r][0] + red[1][r][1] + red[1][r][2] + red[1][r][3];
    fs2[row] = a_ * LOG2E;
    fd2[row] = b_ * LOG2E;
  }
}

// ---------------------------------------------------------------------------
// main v7: R5 numeric path (direct exp2 p, bf16 pack), restructured:
//  - 64 rows per wave (4 A-fragments share each B-fragment load)
//  - NO atomics: per-chunk partial slabs, reduced in fin_kernel
// One wave per (64 rows, 1/8 col chunk) = 2048 waves (all co-resident).
// ---------------------------------------------------------------------------
__global__ __launch_bounds__(256) void gat_main(
    const int* __restrict__ adj, const unsigned short* __restrict__ wpk,
    const float* __restrict__ fs2, const float* __restrict__ fd2,
    float* __restrict__ nump, float* __restrict__ denp)
{
  const int wave  = blockIdx.x * 4 + (threadIdx.x >> 6);
  const int lane  = threadIdx.x & 63;
  const int strip = wave & 255;             // 256 strips of 64 rows
  const int chunk = wave >> 8;              // 8 column chunks
  const int m = lane & 15;
  const int q = lane >> 4;

  int   row[4];
  float fs[4];
  const int4v* __restrict__ arow[4];
#pragma unroll
  for (int g = 0; g < 4; ++g) {
    row[g] = strip * 64 + g * 16 + m;
    fs[g] = fs2[row[g]];
    arow[g] = (const int4v*)(adj + (size_t)row[g] * GN);
  }

  const int CW = GN / NCH;                  // 2048 columns per chunk
  const int j0 = chunk * CW;
  const float4* __restrict__ fdv  = (const float4*)fd2;
  const short8* __restrict__ wpk8 = (const short8*)wpk;

  f32x4 acc[4][4];
  f32x4 accd[4];
#pragma unroll
  for (int g = 0; g < 4; ++g) {
    accd[g] = (f32x4){0.f, 0.f, 0.f, 0.f};
#pragma unroll
    for (int b = 0; b < 4; ++b) acc[g][b] = (f32x4){0.f, 0.f, 0.f, 0.f};
  }

  short8 b_ones;
#pragma unroll
  for (int i = 0; i < 8; ++i) b_ones[i] = (short)0x3F80;  // bf16 1.0

  auto pcalc = [&](int a, float fd, float fsv) -> unsigned short {
    float sv = fsv + fd;
    float lv = fmaxf(sv, 0.02f * sv);       // lrelu (commutes with *log2e)
    float pe = __builtin_amdgcn_exp2f(lv);
    pe = (a != 0) ? pe : 0.f;
    return f2bf(pe);
  };

  auto mk_af = [&](int4v aA, int4v aB, float4 fA, float4 fB, float fsv) -> short8 {
    short8 af;
    af[0] = (short)pcalc(aA.x, fA.x, fsv);
    af[1] = (short)pcalc(aA.y, fA.y, fsv);
    af[2] = (short)pcalc(aA.z, fA.z, fsv);
    af[3] = (short)pcalc(aA.w, fA.w, fsv);
    af[4] = (short)pcalc(aB.x, fB.x, fsv);
    af[5] = (short)pcalc(aB.y, fB.y, fsv);
    af[6] = (short)pcalc(aB.z, fB.z, fsv);
    af[7] = (short)pcalc(aB.w, fB.w, fsv);
    return af;
  };

#pragma unroll 1
  for (int j = j0; j < j0 + CW; j += 32) {
    const int i4 = (j >> 2) + (q << 1);

    // adj: 8 nontemporal 16B loads (4 row groups x 2)
    int4v a0[4], a1[4];
#pragma unroll
    for (int g = 0; g < 4; ++g) {
      a0[g] = __builtin_nontemporal_load(arow[g] + i4);
      a1[g] = __builtin_nontemporal_load(arow[g] + i4 + 1);
    }
    float4 f0 = fdv[i4];
    float4 f1 = fdv[i4 + 1];

    // packed B fragments: 4 contiguous 1 KB wave-loads, shared by 4 A-frags
    const short8* wb = wpk8 + (size_t)(j >> 5) * 512 + lane;
    short8 b0 = wb[0];
    short8 b1 = wb[128];
    short8 b2 = wb[256];
    short8 b3 = wb[384];

#pragma unroll
    for (int g = 0; g < 4; ++g) {
      short8 af = mk_af(a0[g], a1[g], f0, f1, fs[g]);
      acc[g][0] = __builtin_amdgcn_mfma_f32_16x16x32_bf16(af, b0, acc[g][0], 0, 0, 0);
      acc[g][1] = __builtin_amdgcn_mfma_f32_16x16x32_bf16(af, b1, acc[g][1], 0, 0, 0);
      acc[g][2] = __builtin_amdgcn_mfma_f32_16x16x32_bf16(af, b2, acc[g][2], 0, 0, 0);
      acc[g][3] = __builtin_amdgcn_mfma_f32_16x16x32_bf16(af, b3, acc[g][3], 0, 0, 0);
      accd[g]   = __builtin_amdgcn_mfma_f32_16x16x32_bf16(af, b_ones, accd[g], 0, 0, 0);
    }
  }

  // epilogue: plain stores into this chunk's private slab (no atomics)
  float* np = nump + (size_t)chunk * GN * GOUT;
  float* dp = denp + (size_t)chunk * GN;
#pragma unroll
  for (int g = 0; g < 4; ++g) {
    const int orow0 = strip * 64 + g * 16 + q * 4;   // C/D: row = q*4+r, col = m
#pragma unroll
    for (int r = 0; r < 4; ++r) {
      float* nr = np + (size_t)(orow0 + r) * GOUT + m;
      __builtin_nontemporal_store(acc[g][0][r], nr + 0);
      __builtin_nontemporal_store(acc[g][1][r], nr + 16);
      __builtin_nontemporal_store(acc[g][2][r], nr + 32);
      __builtin_nontemporal_store(acc[g][3][r], nr + 48);
      if (m == 0) dp[orow0 + r] = accd[g][r];   // col-independent for B=ones
    }
  }
}

// ---------------------------------------------------------------------------
// finalize: out = elu( (sum_c num_c) / (sum_c den_c) )
// ---------------------------------------------------------------------------
__global__ __launch_bounds__(256) void fin_kernel(
    const float* __restrict__ nump, const float* __restrict__ denp,
    float* __restrict__ out)
{
  const int g = blockIdx.x * 256 + threadIdx.x;
  if (g >= GN * GOUT) return;
  const int row = g >> 6;
  float s = 0.f, d = 0.f;
#pragma unroll
  for (int c = 0; c < NCH; ++c) {
    s += nump[(size_t)c * GN * GOUT + g];
    d += denp[(size_t)c * GN + row];
  }
  float v = s / d;
  out[g] = (v > 0.f) ? v : expm1f(v);
}

extern "C" void kernel_launch(void* const* d_in, const int* in_sizes, int n_in,
                              void* d_out, int out_size, void* d_ws, size_t ws_size,
                              hipStream_t stream) {
  const float* x   = (const float*)d_in[0];
  const int*   adj = (const int*)d_in[1];
  const float* w   = (const float*)d_in[2];
  const float* aw  = (const float*)d_in[3];
  float* out = (float*)d_out;

  // ws layout (floats): nump[8*N*64] | denp[8*N] | fs2[N] | fd2[N] | wpk(bf16 64*N)
  float* nump = (float*)d_ws;
  float* denp = nump + (size_t)NCH * GN * GOUT;
  float* fs2  = denp + (size_t)NCH * GN;
  float* fd2  = fs2 + GN;
  unsigned short* wpk = (unsigned short*)(fd2 + GN);
  // ~37 MB of the ws; everything fully written before read -> no memset needed

  prep_kernel<<<GN / 64, 256, 0, stream>>>(x, w, aw, wpk, fs2, fd2);
  gat_main<<<(GN / 64) * NCH / 4, 256, 0, stream>>>(adj, wpk, fs2, fd2, nump, denp);
  fin_kernel<<<(GN * GOUT) / 256, 256, 0, stream>>>(nump, denp, out);
}